// Round 10
// baseline (170.293 us; speedup 1.0000x reference)
//
#include <hip/hip_runtime.h>
#include <math.h>

// QGRUCell — Round 16: zero-LDS, zero-barrier register-dataflow GEMM.
// Invariant shared by ALL nine prior structures (43-50us): waves coupled
// through LDS + barriers. This kernel removes both: every MFMA fragment
// (A and W) is a direct global_load_dwordx4 at chunk*1024+lane*16 (the ws
// chunk layout IS the fragment layout, proven R9), W-sharing between waves
// handled by L1 instead of LDS. 3-deep register pipeline (f0/f1/f2, fully
// unrolled, static indices), no syncthreads, no dma16, no asm waits —
// compiler emits counted vmcnt for plain-C loads (m131). Numerics
// bit-identical to R13. cvt = R15 verbatim (K-quarter split, 2432 blocks).
// ws: 512-f16 chunks, A: arr*8192+M32*32+K16, W: 16384+(g*16+N32)*32+K16;
// chunk pos(row,k)=(k>>3&1)*256+row*8+(k&7).

typedef _Float16 f16x8  __attribute__((ext_vector_type(8)));
typedef _Float16 f16x4  __attribute__((ext_vector_type(4)));
typedef __bf16   bf16x8 __attribute__((ext_vector_type(8)));
typedef float    f32x16 __attribute__((ext_vector_type(16)));

namespace {

constexpr int Bsz = 8192, Ksz = 512, Hsz = 512;
constexpr int BM = 64, BN = 64;

constexpr unsigned WCH0    = 16384u;
constexpr unsigned NCHUNK  = 16384u + 3072u;          // 19456
constexpr unsigned WS_F16  = NCHUNK * 512u;           // 9,961,472 f16
constexpr size_t   WS_NEED = (size_t)WS_F16 * 2;      // 19,922,944 B

__device__ __forceinline__ float qround(float x, float s, float invs) {
    return floorf(x * s + 0.5f) * invs;
}

__device__ __forceinline__ float qsigmoid_dev(float x) {
    float iq = floorf(x * 134217728.0f + 0.5f);
    iq = fminf(fmaxf(iq, -2147483648.0f), 2147483648.0f);
    float e = __expf(-iq * 7.450580596923828125e-9f);
    float s = __builtin_amdgcn_rcpf(1.0f + e);
    float q31 = floorf(s * 2147483648.0f + 0.5f);
    float q15 = floorf(q31 * 1.52587890625e-5f + 0.5f);
    return q15 * 3.0517578125e-5f;
}

__device__ __forceinline__ float qtanh_dev(float x) {
    float iq = floorf(x * 134217728.0f + 0.5f);
    iq = fminf(fmaxf(iq, -2147483648.0f), 2147483648.0f);
    float z = iq * 7.450580596923828125e-9f;
    float e = __expf(2.0f * z);
    float t = 1.0f - 2.0f * __builtin_amdgcn_rcpf(e + 1.0f);
    float q31 = floorf(t * 2147483648.0f + 0.5f);
    float q15 = floorf(q31 * 1.52587890625e-5f + 0.5f);
    return q15 * 3.0517578125e-5f;
}

__device__ __forceinline__ void split2(float a, float b, unsigned& hi, unsigned& lo) {
    unsigned ua = __float_as_uint(a); ua += 0x7fffu + ((ua >> 16) & 1u);
    unsigned ub = __float_as_uint(b); ub += 0x7fffu + ((ub >> 16) & 1u);
    hi = (ua >> 16) | (ub & 0xffff0000u);
    float ra = a - __uint_as_float(ua & 0xffff0000u);
    float rb = b - __uint_as_float(ub & 0xffff0000u);
    unsigned va = __float_as_uint(ra); va += 0x7fffu + ((va >> 16) & 1u);
    unsigned vb = __float_as_uint(rb); vb += 0x7fffu + ((vb >> 16) & 1u);
    lo = (va >> 16) | (vb & 0xffff0000u);
}

} // namespace

// ---------------- pre-pass: LDS-tile-transpose fp32 -> f16 chunks ----------
// K-quarter split: block b4 = 4*group + kq handles 32 rows x 128 cols.
__global__ __launch_bounds__(256) void cvt_lds_f16(
    const float* __restrict__ x, const float* __restrict__ h,
    const float* __restrict__ wih, const float* __restrict__ whh,
    _Float16* __restrict__ ws)
{
    __shared__ __align__(16) _Float16 lt[4096];   // 8 KB

    const int b4  = blockIdx.x;
    const int b   = b4 >> 2;
    const int kq  = b4 & 3;
    const int tid = threadIdx.x;

    const float* src;      // base of the 32-row group (row-major, stride 512)
    unsigned chbase;       // first chunk index of this group
    if (b < 512) {                         // A: x (arr0), h (arr1)
        const int arr = b >> 8, M32 = b & 255;
        src = (arr ? h : x) + (size_t)M32 * 32u * 512u;
        chbase = (unsigned)arr * 8192u + (unsigned)M32 * 32u;
    } else {                               // W: gate g, col-group N32
        const int w = b - 512;             // 0..95
        const int g = w >> 4, N32 = w & 15;
        const int rowLocal = (g % 3) * 512 + N32 * 32;
        src = (g < 3 ? wih : whh) + (size_t)rowLocal * 512u;
        chbase = WCH0 + (unsigned)((g * 16 + N32) * 32);
    }
    src += kq * 128;                       // K-quarter column offset

    // Phase 1: 4 reps x 256 threads covering 32 rows x 32 float4s
#pragma unroll
    for (int rep = 0; rep < 4; ++rep) {
        const int idx = rep * 256 + tid;       // 0..1023
        const int row = idx >> 5;              // 0..31
        const int q   = idx & 31;              // local float4 col
        const float4 v = *(const float4*)(src + (size_t)row * 512 + q * 4);
        const int K16l = q >> 2;               // 0..7
        const int kh   = (q >> 1) & 1;
        const int half = (q & 1) * 4;
        const int rsw  = (row + (q >> 1)) & 31;
        f16x4 o;
        o[0] = (_Float16)v.x; o[1] = (_Float16)v.y;
        o[2] = (_Float16)v.z; o[3] = (_Float16)v.w;
        *(f16x4*)&lt[K16l * 512 + kh * 256 + rsw * 8 + half] = o;
    }
    __syncthreads();

    // Phase 2: wave wv writes chunks K16l = wv*2, wv*2+1
    const int wv = tid >> 6, lane = tid & 63;
    const int kh = lane >> 5, row = lane & 31;
#pragma unroll
    for (int cc = 0; cc < 2; ++cc) {
        const int K16l = wv * 2 + cc;
        const int rsw  = (row + 2 * K16l + kh) & 31;
        const f16x8 o = *(const f16x8*)&lt[K16l * 512 + kh * 256 + rsw * 8];
        *(f16x8*)(ws + (size_t)(chbase + (unsigned)(kq * 8 + K16l)) * 512u
                      + lane * 8) = o;
    }
}

// ---------------- main: zero-LDS, zero-barrier register dataflow -----------
__global__ __launch_bounds__(256, 2) void qgru_f16_reg(
    const _Float16* __restrict__ ws, const float* __restrict__ hid,
    const float* __restrict__ bih, const float* __restrict__ bhh,
    float* __restrict__ out)
{
    const int t = threadIdx.x, lane = t & 63, wid = t >> 6;
    const int mt = wid >> 1, nt = wid & 1;
    const int m0 = blockIdx.x * BM, n0 = blockIdx.y * BN;

    // 8 fragment streams, each advancing 1KB per k16 step.
    // 0: A arr0 (ax), 1: A arr1 (ah), 2..7: W gates 0..5 (this wave's nt col).
    const char* wsb = (const char*)ws;
    const char* s0 = wsb + (size_t)((unsigned)((m0 >> 5) + mt) * 32u) * 1024u + lane * 16;
    const char* s1 = s0 + (size_t)8192u * 1024u;
    const char* sw[6];
#pragma unroll
    for (int g = 0; g < 6; ++g)
        sw[g] = wsb + (size_t)(WCH0 + (unsigned)((g * 16 + (n0 >> 5) + nt) * 32)) * 1024u
                    + lane * 16;

    f32x16 acc[6];
#pragma unroll
    for (int g = 0; g < 6; ++g)
#pragma unroll
        for (int i = 0; i < 16; ++i) acc[g][i] = 0.0f;

    // 3-deep register pipeline; fully unrolled loop -> all indices static.
    f16x8 f0[8], f1[8], f2[8];

#define LOADSET(F, STEP)                                                     \
    do {                                                                     \
        const size_t o_ = (size_t)(STEP) * 1024u;                            \
        F[0] = *(const f16x8*)(s0 + o_);                                     \
        F[1] = *(const f16x8*)(s1 + o_);                                     \
        F[2] = *(const f16x8*)(sw[0] + o_);                                  \
        F[3] = *(const f16x8*)(sw[1] + o_);                                  \
        F[4] = *(const f16x8*)(sw[2] + o_);                                  \
        F[5] = *(const f16x8*)(sw[3] + o_);                                  \
        F[6] = *(const f16x8*)(sw[4] + o_);                                  \
        F[7] = *(const f16x8*)(sw[5] + o_);                                  \
    } while (0)

#define STEPBODY(F, STEP)                                                    \
    do {                                                                     \
        acc[0] = __builtin_amdgcn_mfma_f32_32x32x16_f16(F[0], F[2], acc[0], 0, 0, 0); \
        acc[1] = __builtin_amdgcn_mfma_f32_32x32x16_f16(F[0], F[3], acc[1], 0, 0, 0); \
        acc[2] = __builtin_amdgcn_mfma_f32_32x32x16_f16(F[0], F[4], acc[2], 0, 0, 0); \
        acc[3] = __builtin_amdgcn_mfma_f32_32x32x16_f16(F[1], F[5], acc[3], 0, 0, 0); \
        acc[4] = __builtin_amdgcn_mfma_f32_32x32x16_f16(F[1], F[6], acc[4], 0, 0, 0); \
        acc[5] = __builtin_amdgcn_mfma_f32_32x32x16_f16(F[1], F[7], acc[5], 0, 0, 0); \
        if ((STEP) + 3 < 32) LOADSET(F, (STEP) + 3);                         \
    } while (0)

    LOADSET(f0, 0);
    LOADSET(f1, 1);
    LOADSET(f2, 2);

#pragma unroll
    for (int step = 0; step < 32; ++step) {
        if ((step % 3) == 0)      STEPBODY(f0, step);
        else if ((step % 3) == 1) STEPBODY(f1, step);
        else                      STEPBODY(f2, step);
    }
#undef STEPBODY
#undef LOADSET

    constexpr float S14 = 16384.0f,     I14 = 1.0f / 16384.0f;
    constexpr float S15 = 32768.0f,     I15 = 1.0f / 32768.0f;
    constexpr float S27 = 134217728.0f, I27 = 1.0f / 134217728.0f;

    const int lh = lane >> 5, l32 = lane & 31;
    const int n = n0 + nt * 32 + l32;
    const float br = bih[n], bi = bih[n + 512], bn = bih[n + 1024];
    const float cr = bhh[n], ci = bhh[n + 512], cn = bhh[n + 1024];

#pragma unroll
    for (int r = 0; r < 16; ++r) {
        const int row = (r & 3) + 8 * (r >> 2) + 4 * lh;
        const int m   = m0 + mt * 32 + row;
        const float hv = hid[(size_t)m * Hsz + n];

        float gir = qround(acc[0][r] + br, S14, I14);
        float gii = qround(acc[1][r] + bi, S14, I14);
        float gin = qround(acc[2][r] + bn, S14, I14);
        float ghr = qround(acc[3][r] + cr, S14, I14);
        float ghi = qround(acc[4][r] + ci, S14, I14);
        float ghn = qround(acc[5][r] + cn, S14, I14);
        float resetg = qsigmoid_dev(gir + ghr);
        float inputg = qsigmoid_dev(gii + ghi);
        float hn  = qround(ghn, S27, I27);
        float rh  = qround(resetg * hn, S15, I15);
        float newg = qtanh_dev(rh + gin);
        float nh  = qround(hv, S15, I15);
        out[(size_t)m * Hsz + n] = newg + inputg * (nh - newg);
    }
}

// ---------------- fallback: bf16x3 (used only if ws too small) -------------
__global__ __launch_bounds__(256, 2) void qgru_mfma_bf16x3(
    const float* __restrict__ x, const float* __restrict__ hid,
    const float* __restrict__ wih, const float* __restrict__ whh,
    const float* __restrict__ bih, const float* __restrict__ bhh,
    float* __restrict__ out)
{
    __shared__ __align__(16) unsigned short lds[16384];

    const int t = threadIdx.x, lane = t & 63, wid = t >> 6;
    const int mt = wid >> 1, nt = wid & 1;
    const int m0 = blockIdx.x * BM, n0 = blockIdx.y * BN;
    const int s_r = t >> 2, s_k = (t & 3) << 2;
    const int s_kh = s_k >> 3, s_j = s_k & 7, s_rt = s_r >> 5, s_r32 = s_r & 31;

    const float* gA[2];
    gA[0] = x   + (size_t)(m0 + s_r) * Ksz + s_k;
    gA[1] = hid + (size_t)(m0 + s_r) * Ksz + s_k;
    const float* gW[6];
#pragma unroll
    for (int g = 0; g < 3; ++g) {
        gW[g]     = wih + (size_t)(g * Hsz + n0 + s_r) * Ksz + s_k;
        gW[g + 3] = whh + (size_t)(g * Hsz + n0 + s_r) * Ksz + s_k;
    }
    const int lh = lane >> 5, l32 = lane & 31;

    f32x16 acc[6];
#pragma unroll
    for (int g = 0; g < 6; ++g)
#pragma unroll
        for (int i = 0; i < 16; ++i) acc[g][i] = 0.0f;

    float4 vA[2], vW[6];
#pragma unroll
    for (int tt = 0; tt < 2; ++tt) vA[tt] = *(const float4*)gA[tt];
#pragma unroll
    for (int g = 0; g < 6; ++g)    vW[g]  = *(const float4*)gW[g];

    for (int k0 = 0; k0 < Ksz; k0 += 16) {
        __syncthreads();
#pragma unroll
        for (int tt = 0; tt < 2; ++tt) {
            unsigned h0, h1, l0, l1;
            split2(vA[tt].x, vA[tt].y, h0, l0);
            split2(vA[tt].z, vA[tt].w, h1, l1);
            unsigned bH = ((((tt*2+0)*2+s_rt)*2+s_kh)*32+s_r32)*8 + s_j;
            unsigned bL = ((((tt*2+1)*2+s_rt)*2+s_kh)*32+s_r32)*8 + s_j;
            *reinterpret_cast<uint2*>(&lds[bH]) = make_uint2(h0, h1);
            *reinterpret_cast<uint2*>(&lds[bL]) = make_uint2(l0, l1);
        }
#pragma unroll
        for (int g = 0; g < 6; ++g) {
            unsigned h0, h1, l0, l1;
            split2(vW[g].x, vW[g].y, h0, l0);
            split2(vW[g].z, vW[g].w, h1, l1);
            unsigned bH = 4096u + ((((g*2+0)*2+s_rt)*2+s_kh)*32+s_r32)*8 + s_j;
            unsigned bL = 4096u + ((((g*2+1)*2+s_rt)*2+s_kh)*32+s_r32)*8 + s_j;
            *reinterpret_cast<uint2*>(&lds[bH]) = make_uint2(h0, h1);
            *reinterpret_cast<uint2*>(&lds[bL]) = make_uint2(l0, l1);
        }
        __syncthreads();
        const int kn = (k0 + 16 < Ksz) ? (k0 + 16) : 0;
#pragma unroll
        for (int tt = 0; tt < 2; ++tt) vA[tt] = *(const float4*)(gA[tt] + kn);
#pragma unroll
        for (int g = 0; g < 6; ++g)    vW[g]  = *(const float4*)(gW[g] + kn);

        const bf16x8 ax_hi = *reinterpret_cast<const bf16x8*>(&lds[((((0)*2+mt)*2+lh)*32+l32)*8]);
        const bf16x8 ax_lo = *reinterpret_cast<const bf16x8*>(&lds[((((1)*2+mt)*2+lh)*32+l32)*8]);
        const bf16x8 ah_hi = *reinterpret_cast<const bf16x8*>(&lds[((((2)*2+mt)*2+lh)*32+l32)*8]);
        const bf16x8 ah_lo = *reinterpret_cast<const bf16x8*>(&lds[((((3)*2+mt)*2+lh)*32+l32)*8]);
#pragma unroll
        for (int g = 0; g < 6; ++g) {
            const bf16x8 b_hi = *reinterpret_cast<const bf16x8*>(&lds[4096u + ((((g*2+0)*2+nt)*2+lh)*32+l32)*8]);
            const bf16x8 b_lo = *reinterpret_cast<const bf16x8*>(&lds[4096u + ((((g*2+1)*2+nt)*2+lh)*32+l32)*8]);
            const bf16x8 a_hi = (g < 3) ? ax_hi : ah_hi;
            const bf16x8 a_lo = (g < 3) ? ax_lo : ah_lo;
            acc[g] = __builtin_amdgcn_mfma_f32_32x32x16_bf16(a_hi, b_hi, acc[g], 0, 0, 0);
            acc[g] = __builtin_amdgcn_mfma_f32_32x32x16_bf16(a_hi, b_lo, acc[g], 0, 0, 0);
            acc[g] = __builtin_amdgcn_mfma_f32_32x32x16_bf16(a_lo, b_hi, acc[g], 0, 0, 0);
        }
    }

    constexpr float S14 = 16384.0f,     I14 = 1.0f / 16384.0f;
    constexpr float S15 = 32768.0f,     I15 = 1.0f / 32768.0f;
    constexpr float S27 = 134217728.0f, I27 = 1.0f / 134217728.0f;
    const int n = n0 + nt * 32 + l32;
    const float br = bih[n], bi = bih[n + 512], bn = bih[n + 1024];
    const float cr = bhh[n], ci = bhh[n + 512], cn = bhh[n + 1024];
#pragma unroll
    for (int r = 0; r < 16; ++r) {
        const int row = (r & 3) + 8 * (r >> 2) + 4 * lh;
        const int m   = m0 + mt * 32 + row;
        const float hv = hid[(size_t)m * Hsz + n];
        float gir = qround(acc[0][r] + br, S14, I14);
        float gii = qround(acc[1][r] + bi, S14, I14);
        float gin = qround(acc[2][r] + bn, S14, I14);
        float ghr = qround(acc[3][r] + cr, S14, I14);
        float ghi = qround(acc[4][r] + ci, S14, I14);
        float ghn = qround(acc[5][r] + cn, S14, I14);
        float resetg = qsigmoid_dev(gir + ghr);
        float inputg = qsigmoid_dev(gii + ghi);
        float hn  = qround(ghn, S27, I27);
        float rh  = qround(resetg * hn, S15, I15);
        float newg = qtanh_dev(rh + gin);
        float nh  = qround(hv, S15, I15);
        out[(size_t)m * Hsz + n] = newg + inputg * (nh - newg);
    }
}

extern "C" void kernel_launch(void* const* d_in, const int* in_sizes, int n_in,
                              void* d_out, int out_size, void* d_ws, size_t ws_size,
                              hipStream_t stream) {
    const float* x   = (const float*)d_in[0];
    const float* hid = (const float*)d_in[1];
    const float* wih = (const float*)d_in[2];
    const float* whh = (const float*)d_in[3];
    const float* bih = (const float*)d_in[4];
    const float* bhh = (const float*)d_in[5];
    float* out = (float*)d_out;
    dim3 grid(Bsz / BM, Hsz / BN);   // 128 x 8 = 1024 blocks

    if (ws_size >= WS_NEED) {
        cvt_lds_f16<<<2432, 256, 0, stream>>>(
            x, hid, wih, whh, (_Float16*)d_ws);
        qgru_f16_reg<<<grid, dim3(256), 0, stream>>>(
            (const _Float16*)d_ws, hid, bih, bhh, out);
    } else {
        qgru_mfma_bf16x3<<<grid, dim3(256), 0, stream>>>(
            x, hid, wih, whh, bih, bhh, out);
    }
}